// Round 1
// baseline (397.433 us; speedup 1.0000x reference)
//
#include <hip/hip_runtime.h>
#include <hip/hip_bf16.h>

// Problem constants (B=4,T=16,N=64,D=256, H=4 heads, hd=64) — all fp32 I/O
#define BATCH 64          // B*T
#define NRES 64           // N
#define DMODEL 256        // D
#define ROWS (BATCH*NRES) // 4096
#define QKVC 768          // 3*D
#define SCALE 0.125f      // 1/sqrt(64)
#define LDP 68            // padded LDS leading dim: b128-aligned, conflict-benign

// native clang vector type — accepted by __builtin_nontemporal_load
typedef float floatx4 __attribute__((ext_vector_type(4)));

// ---------------------------------------------------------------------------
// Kernel 1: qkv = x @ Wqkv + bqkv.  (4096x256)@(256x768) fp32, 64x64 tiles.
// A staged transposed (AsT[c][r], stride 68) -> A-fragment = one ds_read_b128.
// ---------------------------------------------------------------------------
__global__ __launch_bounds__(256) void qkv_gemm(
    const float* __restrict__ x, const float* __restrict__ W,
    const float* __restrict__ bq, float* __restrict__ qkv) {
  __shared__ float AsT[64 * LDP];  // [c][r]
  __shared__ float Bs[64 * LDP];   // [r][c]
  int t = threadIdx.x;
  int tx = t & 15, ty = t >> 4;
  int rowBase = blockIdx.y * 64;
  int colBase = blockIdx.x * 64;
  float acc[4][4] = {};
  for (int kb = 0; kb < 256; kb += 64) {
#pragma unroll
    for (int p = 0; p < 4; ++p) {
      int e = (p * 256 + t) * 4;
      int r = e >> 6, c = e & 63;
      float4 av = *(const float4*)&x[(size_t)(rowBase + r) * 256 + kb + c];
      AsT[(c + 0) * LDP + r] = av.x;
      AsT[(c + 1) * LDP + r] = av.y;
      AsT[(c + 2) * LDP + r] = av.z;
      AsT[(c + 3) * LDP + r] = av.w;
      *(float4*)&Bs[r * LDP + c] =
          *(const float4*)&W[(size_t)(kb + r) * QKVC + colBase + c];
    }
    __syncthreads();
#pragma unroll 4
    for (int kk = 0; kk < 64; ++kk) {
      float4 a4 = *(const float4*)&AsT[kk * LDP + ty * 4];
      float4 b4 = *(const float4*)&Bs[kk * LDP + tx * 4];
      float a[4] = {a4.x, a4.y, a4.z, a4.w};
      float b[4] = {b4.x, b4.y, b4.z, b4.w};
#pragma unroll
      for (int i = 0; i < 4; ++i)
#pragma unroll
        for (int j = 0; j < 4; ++j) acc[i][j] += a[i] * b[j];
    }
    __syncthreads();
  }
#pragma unroll
  for (int i = 0; i < 4; ++i) {
    int r = rowBase + ty * 4 + i;
#pragma unroll
    for (int j = 0; j < 4; ++j) {
      int c = colBase + tx * 4 + j;
      qkv[(size_t)r * QKVC + c] = acc[i][j] + bq[c];
    }
  }
}

// ---------------------------------------------------------------------------
// Kernel 2 (fused): per-(b,n) relational attention, qk fused in.
//  - branchless mask-skip: masked rows redirect their load to row 0 (cache-hot)
//    so all 16 bias loads + 16 k loads issue without control flow -> deep MLP.
//  - q.k computed in-block with the same shfl-reduce structure (k rows from L2)
//    -> qk_gemm kernel + 8 MB of qk workspace traffic eliminated.
//  - AV vectorized: thread = 4 channels (floatx4 v loads), m split over waves,
//    4-way LDS reduction.
//  - XCD swizzle: 64 blocks sharing a batch's k/v land on one XCD's L2.
// ---------------------------------------------------------------------------
__global__ __launch_bounds__(256) void attn_kernel(
    const float* __restrict__ bias, const int* __restrict__ mask,
    const float* __restrict__ qkv, float* __restrict__ ctx) {
  __shared__ float q_s[256];
  __shared__ int mask_s[64];
  __shared__ float rel_s[256];   // [h][m] geometry-bias scores
  __shared__ float qks_s[256];   // [h][m] q.k scores
  __shared__ float attn_s[256];  // [h][m] softmax probs
  __shared__ float red_s[4][256];// AV partial sums per wave
  int t = threadIdx.x;
  // XCD-aware swizzle: consecutive logical ids round-robin XCDs; give each XCD
  // a contiguous range of blk so same-batch blocks share an L2 (4096 % 8 == 0).
  int logical = blockIdx.x;
  int blk = (logical & 7) * 512 + (logical >> 3);  // b*64+n
  int b = blk >> 6;
  int m = t & 63, h = t >> 6;
  int msk = mask[b * 64 + m];
  if (t < 64) mask_s[t] = mask[b * 64 + t];
  q_s[t] = qkv[(size_t)blk * QKVC + t];  // q = first 256 cols
  __syncthreads();
  int wave = t >> 6, lane = t & 63;
  int hseg = lane >> 4;  // which head this lane's channels belong to
  float4 qv = *(const float4*)&q_s[lane * 4];
  const floatx4* brow_base =
      (const floatx4*)(bias + (size_t)blk * 64 * 256);
  const floatx4* krow_base =
      (const floatx4*)(qkv + (size_t)b * 64 * QKVC + 256);  // k cols
#pragma unroll
  for (int i = 0; i < 16; ++i) {
    int mm = i * 4 + wave;
    // branchless skip: masked rows read row 0 instead (1KB, stays cached);
    // their rel value is garbage but the logit ternary never selects it.
    int src = mask_s[mm] ? mm : 0;
    floatx4 bv = __builtin_nontemporal_load(&brow_base[src * 64 + lane]);
    floatx4 kv = krow_base[(size_t)mm * (QKVC / 4) + lane];  // L2-hot
    float p = bv.x * qv.x + bv.y * qv.y + bv.z * qv.z + bv.w * qv.w;
    float s = kv.x * qv.x + kv.y * qv.y + kv.z * qv.z + kv.w * qv.w;
    p += __shfl_xor(p, 1, 64);
    s += __shfl_xor(s, 1, 64);
    p += __shfl_xor(p, 2, 64);
    s += __shfl_xor(s, 2, 64);
    p += __shfl_xor(p, 4, 64);
    s += __shfl_xor(s, 4, 64);
    p += __shfl_xor(p, 8, 64);
    s += __shfl_xor(s, 8, 64);
    if ((lane & 15) == 0) {
      rel_s[hseg * 64 + mm] = p;
      qks_s[hseg * 64 + mm] = s;
    }
  }
  __syncthreads();
  float rel = rel_s[h * 64 + m];
  float s_qk = qks_s[h * 64 + m];
  float logit = s_qk * SCALE + (msk ? rel * SCALE : -1e9f);
  // wave-wide (64 lane) softmax over m
  float mx = logit;
#pragma unroll
  for (int off = 32; off > 0; off >>= 1) mx = fmaxf(mx, __shfl_xor(mx, off, 64));
  float ex = __expf(logit - mx);
  float sm = ex;
#pragma unroll
  for (int off = 32; off > 0; off >>= 1) sm += __shfl_xor(sm, off, 64);
  attn_s[h * 64 + m] = ex / sm;
  __syncthreads();
  // AV: wave handles m in [wave*16, wave*16+16); thread covers channels lane*4..+3
  int c4 = lane * 4;
  int hh = lane >> 4;  // head of this thread's channel group
  floatx4 acc = {0.f, 0.f, 0.f, 0.f};
  const float* vb = qkv + (size_t)b * 64 * QKVC + 512 + c4;
#pragma unroll
  for (int i = 0; i < 16; ++i) {
    int mm = wave * 16 + i;
    float a = attn_s[hh * 64 + mm];
    floatx4 vv = *(const floatx4*)&vb[(size_t)mm * QKVC];
    acc.x += a * vv.x; acc.y += a * vv.y; acc.z += a * vv.z; acc.w += a * vv.w;
  }
  *(floatx4*)&red_s[wave][c4] = acc;
  __syncthreads();
  ctx[(size_t)blk * 256 + t] =
      red_s[0][t] + red_s[1][t] + red_s[2][t] + red_s[3][t];
}

// ---------------------------------------------------------------------------
// Kernel 3: out = ctx @ Wproj + bproj -> fp32. Transposed-A staging.
// ---------------------------------------------------------------------------
__global__ __launch_bounds__(256) void proj_gemm(
    const float* __restrict__ ctx, const float* __restrict__ W,
    const float* __restrict__ bp, float* __restrict__ out) {
  __shared__ float AsT[64 * LDP];
  __shared__ float Bs[64 * LDP];
  int t = threadIdx.x;
  int tx = t & 15, ty = t >> 4;
  int rowBase = blockIdx.y * 64;
  int colBase = blockIdx.x * 64;
  float acc[4][4] = {};
  for (int kb = 0; kb < 256; kb += 64) {
#pragma unroll
    for (int p = 0; p < 4; ++p) {
      int e = (p * 256 + t) * 4;
      int r = e >> 6, c = e & 63;
      float4 av = *(const float4*)&ctx[(size_t)(rowBase + r) * 256 + kb + c];
      AsT[(c + 0) * LDP + r] = av.x;
      AsT[(c + 1) * LDP + r] = av.y;
      AsT[(c + 2) * LDP + r] = av.z;
      AsT[(c + 3) * LDP + r] = av.w;
      *(float4*)&Bs[r * LDP + c] =
          *(const float4*)&W[(size_t)(kb + r) * 256 + colBase + c];
    }
    __syncthreads();
#pragma unroll 4
    for (int kk = 0; kk < 64; ++kk) {
      float4 a4 = *(const float4*)&AsT[kk * LDP + ty * 4];
      float4 b4 = *(const float4*)&Bs[kk * LDP + tx * 4];
      float a[4] = {a4.x, a4.y, a4.z, a4.w};
      float b[4] = {b4.x, b4.y, b4.z, b4.w};
#pragma unroll
      for (int i = 0; i < 4; ++i)
#pragma unroll
        for (int j = 0; j < 4; ++j) acc[i][j] += a[i] * b[j];
    }
    __syncthreads();
  }
#pragma unroll
  for (int i = 0; i < 4; ++i) {
    int r = rowBase + ty * 4 + i;
#pragma unroll
    for (int j = 0; j < 4; ++j) {
      int c = colBase + tx * 4 + j;
      out[(size_t)r * 256 + c] = acc[i][j] + bp[c];
    }
  }
}

extern "C" void kernel_launch(void* const* d_in, const int* in_sizes, int n_in,
                              void* d_out, int out_size, void* d_ws, size_t ws_size,
                              hipStream_t stream) {
  // setup_inputs order: x, bias_features, mask, Wqkv, bqkv, Wproj, bproj
  const float* x    = (const float*)d_in[0];
  const float* bias = (const float*)d_in[1];
  const int*   mask = (const int*)d_in[2];
  const float* Wqkv = (const float*)d_in[3];
  const float* bqkv = (const float*)d_in[4];
  const float* Wprj = (const float*)d_in[5];
  const float* bprj = (const float*)d_in[6];
  float* out = (float*)d_out;

  // workspace layout (fp32): qkv (4096x768) | ctx (4096x256)
  float* qkv_ws = (float*)d_ws;
  float* ctx_ws = qkv_ws + (size_t)ROWS * QKVC;

  qkv_gemm<<<dim3(12, 64), 256, 0, stream>>>(x, Wqkv, bqkv, qkv_ws);
  attn_kernel<<<ROWS, 256, 0, stream>>>(bias, mask, qkv_ws, ctx_ws);
  proj_gemm<<<dim3(4, 64), 256, 0, stream>>>(ctx_ws, Wprj, bprj, out);
}

// Round 2
// 385.755 us; speedup vs baseline: 1.0303x; 1.0303x over previous
//
#include <hip/hip_runtime.h>

// Problem constants (B=4,T=16,N=64,D=256, H=4 heads, hd=64) — all fp32 I/O
#define BATCH 64          // B*T
#define NRES 64           // N
#define DMODEL 256        // D
#define ROWS (BATCH*NRES) // 4096
#define QKVC 768          // 3*D
#define SCALE 0.125f      // 1/sqrt(64)
#define LDP 68            // padded LDS leading dim: b128-aligned, conflict-benign

// native clang vector type — accepted by __builtin_nontemporal_load
typedef float floatx4 __attribute__((ext_vector_type(4)));

// ---------------------------------------------------------------------------
// Kernel 1: qkv = x @ Wqkv + bqkv.  (4096x256)@(256x768) fp32, 64x64 tiles.
// A staged transposed (AsT[c][r], stride 68) -> A-fragment = one ds_read_b128.
// ---------------------------------------------------------------------------
__global__ __launch_bounds__(256) void qkv_gemm(
    const float* __restrict__ x, const float* __restrict__ W,
    const float* __restrict__ bq, float* __restrict__ qkv) {
  __shared__ float AsT[64 * LDP];  // [c][r]
  __shared__ float Bs[64 * LDP];   // [r][c]
  int t = threadIdx.x;
  int tx = t & 15, ty = t >> 4;
  int rowBase = blockIdx.y * 64;
  int colBase = blockIdx.x * 64;
  float acc[4][4] = {};
  for (int kb = 0; kb < 256; kb += 64) {
#pragma unroll
    for (int p = 0; p < 4; ++p) {
      int e = (p * 256 + t) * 4;
      int r = e >> 6, c = e & 63;
      float4 av = *(const float4*)&x[(size_t)(rowBase + r) * 256 + kb + c];
      AsT[(c + 0) * LDP + r] = av.x;
      AsT[(c + 1) * LDP + r] = av.y;
      AsT[(c + 2) * LDP + r] = av.z;
      AsT[(c + 3) * LDP + r] = av.w;
      *(float4*)&Bs[r * LDP + c] =
          *(const float4*)&W[(size_t)(kb + r) * QKVC + colBase + c];
    }
    __syncthreads();
#pragma unroll 4
    for (int kk = 0; kk < 64; ++kk) {
      float4 a4 = *(const float4*)&AsT[kk * LDP + ty * 4];
      float4 b4 = *(const float4*)&Bs[kk * LDP + tx * 4];
      float a[4] = {a4.x, a4.y, a4.z, a4.w};
      float b[4] = {b4.x, b4.y, b4.z, b4.w};
#pragma unroll
      for (int i = 0; i < 4; ++i)
#pragma unroll
        for (int j = 0; j < 4; ++j) acc[i][j] += a[i] * b[j];
    }
    __syncthreads();
  }
#pragma unroll
  for (int i = 0; i < 4; ++i) {
    int r = rowBase + ty * 4 + i;
#pragma unroll
    for (int j = 0; j < 4; ++j) {
      int c = colBase + tx * 4 + j;
      qkv[(size_t)r * QKVC + c] = acc[i][j] + bq[c];
    }
  }
}

// ---------------------------------------------------------------------------
// Kernel 2 (fused): per-(b,n) relational attention with qk fused in.
//  - COMPACTED mask-skip: wave 0 ballots the mask into a dense index list
//    idx_s[0..cnt). The bias/k loop walks only real rows: zero divergent
//    branches in the load path, zero redundant loads (round-1's NT redirect
//    to row 0 re-fetched ~134 MB from HBM — that bug is gone).
//  - masked rows never touch rel_s/qks_s: logit = msk ? (qk+rel)*s : -1e9
//    (identical under fp32 exp underflow; k-dots also skipped for masked).
//  - 2 rows/wave/iter (4 loads in flight) for memory-level parallelism.
//  - AV vectorized: thread = 4 channels, m split over waves, LDS reduction.
//  - XCD swizzle: 64 blocks sharing a batch's k/v land on one XCD's L2.
// ---------------------------------------------------------------------------
__global__ __launch_bounds__(256) void attn_kernel(
    const float* __restrict__ bias, const int* __restrict__ mask,
    const float* __restrict__ qkv, float* __restrict__ ctx) {
  __shared__ float q_s[256];
  __shared__ int mask_s[64];
  __shared__ int idx_s[64];
  __shared__ int cnt_s;
  __shared__ float rel_s[256];   // [h][m] geometry-bias scores (unmasked only)
  __shared__ float qks_s[256];   // [h][m] q.k scores (unmasked only)
  __shared__ float attn_s[256];  // [h][m] softmax probs
  __shared__ float red_s[4][256];// AV partial sums per wave
  int t = threadIdx.x;
  // XCD-aware swizzle (4096 % 8 == 0): each XCD gets a contiguous blk range.
  int logical = blockIdx.x;
  int blk = (logical & 7) * 512 + (logical >> 3);  // b*64+n
  int b = blk >> 6;
  int m = t & 63, h = t >> 6;
  if (t < 64) {  // wave 0: mask load + ballot-compaction of unmasked rows
    int mk = mask[b * 64 + t];
    mask_s[t] = mk;
    unsigned long long bal = __ballot(mk != 0);
    int pos = __popcll(bal & ((1ull << t) - 1ull));
    if (mk) idx_s[pos] = t;
    if (t == 0) cnt_s = (int)__popcll(bal);
  }
  q_s[t] = qkv[(size_t)blk * QKVC + t];  // q = first 256 cols
  __syncthreads();
  int wave = t >> 6, lane = t & 63;
  int hseg = lane >> 4;  // which head this lane's channels belong to
  float4 qv = *(const float4*)&q_s[lane * 4];
  const floatx4* brow_base =
      (const floatx4*)(bias + (size_t)blk * 64 * 256);
  const floatx4* krow_base =
      (const floatx4*)(qkv + (size_t)b * 64 * QKVC + 256);  // k cols
  int cnt = cnt_s;
  // 8 compacted rows per iteration: 2 per wave -> 4 loads in flight/wave
  for (int i0 = 0; i0 < cnt; i0 += 8) {
    int iA = i0 + wave;
    int iB = i0 + 4 + wave;
    if (iA < cnt) {                       // wave-uniform branch
      int mmA = idx_s[iA];
      bool doB = (iB < cnt);              // wave-uniform
      int mmB = doB ? idx_s[iB] : mmA;
      floatx4 bvA = __builtin_nontemporal_load(&brow_base[mmA * 64 + lane]);
      floatx4 kvA = krow_base[(size_t)mmA * (QKVC / 4) + lane];
      floatx4 bvB = __builtin_nontemporal_load(&brow_base[mmB * 64 + lane]);
      floatx4 kvB = krow_base[(size_t)mmB * (QKVC / 4) + lane];
      float pA = bvA.x * qv.x + bvA.y * qv.y + bvA.z * qv.z + bvA.w * qv.w;
      float sA = kvA.x * qv.x + kvA.y * qv.y + kvA.z * qv.z + kvA.w * qv.w;
      float pB = bvB.x * qv.x + bvB.y * qv.y + bvB.z * qv.z + bvB.w * qv.w;
      float sB = kvB.x * qv.x + kvB.y * qv.y + kvB.z * qv.z + kvB.w * qv.w;
#pragma unroll
      for (int off = 1; off <= 8; off <<= 1) {
        pA += __shfl_xor(pA, off, 64);
        sA += __shfl_xor(sA, off, 64);
        pB += __shfl_xor(pB, off, 64);
        sB += __shfl_xor(sB, off, 64);
      }
      if ((lane & 15) == 0) {
        rel_s[hseg * 64 + mmA] = pA;
        qks_s[hseg * 64 + mmA] = sA;
        if (doB) {
          rel_s[hseg * 64 + mmB] = pB;
          qks_s[hseg * 64 + mmB] = sB;
        }
      }
    }
  }
  __syncthreads();
  float logit = -1e9f;
  if (mask_s[m]) logit = (qks_s[h * 64 + m] + rel_s[h * 64 + m]) * SCALE;
  // wave-wide (64 lane) softmax over m
  float mx = logit;
#pragma unroll
  for (int off = 32; off > 0; off >>= 1) mx = fmaxf(mx, __shfl_xor(mx, off, 64));
  float ex = __expf(logit - mx);
  float sm = ex;
#pragma unroll
  for (int off = 32; off > 0; off >>= 1) sm += __shfl_xor(sm, off, 64);
  attn_s[h * 64 + m] = ex / sm;
  __syncthreads();
  // AV: wave handles m in [wave*16, wave*16+16); thread covers channels lane*4..+3
  int c4 = lane * 4;
  int hh = lane >> 4;  // head of this thread's channel group
  floatx4 acc = {0.f, 0.f, 0.f, 0.f};
  const float* vb = qkv + (size_t)b * 64 * QKVC + 512 + c4;
#pragma unroll
  for (int i = 0; i < 16; ++i) {
    int mm = wave * 16 + i;
    float a = attn_s[hh * 64 + mm];
    floatx4 vv = *(const floatx4*)&vb[(size_t)mm * QKVC];
    acc.x += a * vv.x; acc.y += a * vv.y; acc.z += a * vv.z; acc.w += a * vv.w;
  }
  *(floatx4*)&red_s[wave][c4] = acc;
  __syncthreads();
  ctx[(size_t)blk * 256 + t] =
      red_s[0][t] + red_s[1][t] + red_s[2][t] + red_s[3][t];
}

// ---------------------------------------------------------------------------
// Kernel 3: out = ctx @ Wproj + bproj -> fp32. Transposed-A staging.
// ---------------------------------------------------------------------------
__global__ __launch_bounds__(256) void proj_gemm(
    const float* __restrict__ ctx, const float* __restrict__ W,
    const float* __restrict__ bp, float* __restrict__ out) {
  __shared__ float AsT[64 * LDP];
  __shared__ float Bs[64 * LDP];
  int t = threadIdx.x;
  int tx = t & 15, ty = t >> 4;
  int rowBase = blockIdx.y * 64;
  int colBase = blockIdx.x * 64;
  float acc[4][4] = {};
  for (int kb = 0; kb < 256; kb += 64) {
#pragma unroll
    for (int p = 0; p < 4; ++p) {
      int e = (p * 256 + t) * 4;
      int r = e >> 6, c = e & 63;
      float4 av = *(const float4*)&ctx[(size_t)(rowBase + r) * 256 + kb + c];
      AsT[(c + 0) * LDP + r] = av.x;
      AsT[(c + 1) * LDP + r] = av.y;
      AsT[(c + 2) * LDP + r] = av.z;
      AsT[(c + 3) * LDP + r] = av.w;
      *(float4*)&Bs[r * LDP + c] =
          *(const float4*)&W[(size_t)(kb + r) * 256 + colBase + c];
    }
    __syncthreads();
#pragma unroll 4
    for (int kk = 0; kk < 64; ++kk) {
      float4 a4 = *(const float4*)&AsT[kk * LDP + ty * 4];
      float4 b4 = *(const float4*)&Bs[kk * LDP + tx * 4];
      float a[4] = {a4.x, a4.y, a4.z, a4.w};
      float b[4] = {b4.x, b4.y, b4.z, b4.w};
#pragma unroll
      for (int i = 0; i < 4; ++i)
#pragma unroll
        for (int j = 0; j < 4; ++j) acc[i][j] += a[i] * b[j];
    }
    __syncthreads();
  }
#pragma unroll
  for (int i = 0; i < 4; ++i) {
    int r = rowBase + ty * 4 + i;
#pragma unroll
    for (int j = 0; j < 4; ++j) {
      int c = colBase + tx * 4 + j;
      out[(size_t)r * 256 + c] = acc[i][j] + bp[c];
    }
  }
}

extern "C" void kernel_launch(void* const* d_in, const int* in_sizes, int n_in,
                              void* d_out, int out_size, void* d_ws, size_t ws_size,
                              hipStream_t stream) {
  // setup_inputs order: x, bias_features, mask, Wqkv, bqkv, Wproj, bproj
  const float* x    = (const float*)d_in[0];
  const float* bias = (const float*)d_in[1];
  const int*   mask = (const int*)d_in[2];
  const float* Wqkv = (const float*)d_in[3];
  const float* bqkv = (const float*)d_in[4];
  const float* Wprj = (const float*)d_in[5];
  const float* bprj = (const float*)d_in[6];
  float* out = (float*)d_out;

  // workspace layout (fp32): qkv (4096x768) | ctx (4096x256)
  float* qkv_ws = (float*)d_ws;
  float* ctx_ws = qkv_ws + (size_t)ROWS * QKVC;

  qkv_gemm<<<dim3(12, 64), 256, 0, stream>>>(x, Wqkv, bqkv, qkv_ws);
  attn_kernel<<<ROWS, 256, 0, stream>>>(bias, mask, qkv_ws, ctx_ws);
  proj_gemm<<<dim3(4, 64), 256, 0, stream>>>(ctx_ws, Wprj, bprj, out);
}